// Round 15
// baseline (662.823 us; speedup 1.0000x reference)
//
#include <hip/hip_runtime.h>
#include <hip/hip_bf16.h>

#define DI __device__ __forceinline__

typedef __attribute__((ext_vector_type(8))) short short8;
typedef __attribute__((ext_vector_type(4))) float f32x4;

DI unsigned short f2bf(float f) {
    union { float f; unsigned int u; } v; v.f = f;
    unsigned int r = v.u + 0x7FFFu + ((v.u >> 16) & 1u);
    return (unsigned short)(r >> 16);
}
DI float bf2f(unsigned short h) {
    union { unsigned int u; float f; } v; v.u = ((unsigned int)h) << 16;
    return v.f;
}

#define GLD16(g, l) __builtin_amdgcn_global_load_lds( \
    (const __attribute__((address_space(1))) void*)(g), \
    (__attribute__((address_space(3))) void*)(l), 16, 0, 0)

// ---------------------------------------------------------------------------
// 256x256 4-phase NT GEMM, BK=64, 8 waves (2Mx4N), 128KiB LDS.  (r13 core.)
// C[i][j] = sum_k A[i][k] * Bt[j][k]
// Swizzle LDS[r][p] = G[r][p ^ ((r>>1)&3)] (conflict-free).  XCD chunking
// (bijective, requires nwg%8==0 -> gated by doswz).  NT full-line stores.
// QKV group 2 writes output directly transposed ([b][col][m]) -- used for
// Ut = (x.Wvr + bvr)^T, consumed by the final PV-out GEMM.
// EPI: 0 = +bias->bf16(NT), 2 = bf16, 3 = +bias->f32(NT)
// ---------------------------------------------------------------------------
template<int EPI, int QKV>
__global__ __launch_bounds__(512, 2) void gemm256(
    const unsigned short* __restrict__ A, const unsigned short* __restrict__ Bt,
    void* __restrict__ Cout, const float* __restrict__ bias,
    const float* __restrict__ bias1, const float* __restrict__ bias2,
    int K, int lda, int ldb, int ldc,
    long sA, long sB, long sC, int doswz)
{
    __shared__ unsigned short lds[65536];   // 128 KiB

    const unsigned gx = gridDim.x, gy = gridDim.y;
    unsigned lin = blockIdx.x + gx * (blockIdx.y + gy * blockIdx.z);
    if (doswz) {
        const unsigned nwg = gx * gy * gridDim.z;   // must be %8==0
        lin = (lin & 7u) * (nwg >> 3) + (lin >> 3);
    }
    int tn = lin % gx;
    const int tm = (lin / gx) % gy;
    const int z = lin / (gx * gy);

    int gsel = 0;
    if (QKV) {
        gsel = tn / 5; tn -= gsel * 5;
        Bt += (size_t)gsel * sB;
        Cout = (void*)((unsigned short*)Cout + (size_t)gsel * sC);
        if (gsel == 1) bias = bias1; else if (gsel == 2) bias = bias2;
    }

    const unsigned short* Ab = A + (long)z * sA + (size_t)(tm * 256) * lda;
    const unsigned short* Bb = Bt + (QKV ? 0 : (long)z * sB) + (size_t)(tn * 256) * ldb;

    const int tid = threadIdx.x, wave = tid >> 6, l = tid & 63;
    const int wr = wave >> 2, wc = wave & 3;    // 2 x 4 wave grid

    const int srow = wave * 32 + (l >> 2);
    const int schunk = ((l & 3) ^ ((l >> 3) & 3)) * 8;
    const unsigned short* agS = Ab + (size_t)srow * lda + schunk;
    const unsigned short* bgS = Bb + (size_t)srow * ldb + schunk;
    unsigned short* ldsA0 = &lds[wave * 1024];
    unsigned short* ldsB0 = &lds[8192 + wave * 1024];

    const int rl = l & 15;
    const int cl8 = ((l >> 4) ^ ((l >> 1) & 3)) * 8;
    const int aoff = (wr * 128 + rl) * 32 + cl8;
    const int boff = 8192 + (wc * 64 + rl) * 32 + cl8;

#define REGOFF(buf, h) (((buf) * 2 + (h)) * 16384)
#define SA(t, h, buf) { const unsigned short* g_ = agS + (size_t)((t) * 64 + (h) * 32); \
    GLD16(g_, ldsA0 + REGOFF(buf, h)); \
    GLD16(g_ + (size_t)16 * lda, ldsA0 + REGOFF(buf, h) + 512); }
#define SB(t, h, buf) { const unsigned short* g_ = bgS + (size_t)((t) * 64 + (h) * 32); \
    GLD16(g_, ldsB0 + REGOFF(buf, h)); \
    GLD16(g_ + (size_t)16 * ldb, ldsB0 + REGOFF(buf, h) + 512); }

    f32x4 acc[8][4] = {};

#define PHASE(buf, h, STG, VMW) { \
    short8 af[8], bfv[4]; \
    _Pragma("unroll") for (int i = 0; i < 4; ++i) \
        af[i] = *(const short8*)&lds[REGOFF(buf, h) + aoff + i * 512]; \
    _Pragma("unroll") for (int n = 0; n < 4; ++n) \
        bfv[n] = *(const short8*)&lds[REGOFF(buf, h) + boff + n * 512]; \
    _Pragma("unroll") for (int i = 4; i < 8; ++i) \
        af[i] = *(const short8*)&lds[REGOFF(buf, h) + aoff + i * 512]; \
    STG; \
    __builtin_amdgcn_s_setprio(1); \
    _Pragma("unroll") for (int i = 0; i < 8; ++i) \
        _Pragma("unroll") for (int n = 0; n < 4; ++n) \
            acc[i][n] = __builtin_amdgcn_mfma_f32_16x16x32_bf16( \
                af[i], bfv[n], acc[i][n], 0, 0, 0); \
    __builtin_amdgcn_s_setprio(0); \
    asm volatile("s_waitcnt " VMW ::: "memory"); \
    __builtin_amdgcn_s_barrier(); \
  }

    SA(0, 0, 0); SB(0, 0, 0); SA(0, 1, 0); SB(0, 1, 0); SA(1, 0, 1); SB(1, 0, 1);
    asm volatile("s_waitcnt vmcnt(8)" ::: "memory");
    __builtin_amdgcn_s_barrier();

    const int NI = K >> 7;
    for (int j = 0; j < NI - 1; ++j) {
        const int t = 2 * j;
        PHASE(0, 0, SA(t + 1, 1, 1) SB(t + 1, 1, 1), "vmcnt(8)")
        PHASE(0, 1, SA(t + 2, 0, 0) SB(t + 2, 0, 0), "vmcnt(8)")
        PHASE(1, 0, SA(t + 2, 1, 0) SB(t + 2, 1, 0), "vmcnt(8)")
        PHASE(1, 1, SA(t + 3, 0, 1) SB(t + 3, 0, 1), "vmcnt(8)")
    }
    {
        const int t = 2 * (NI - 1);
        PHASE(0, 0, SA(t + 1, 1, 1) SB(t + 1, 1, 1), "vmcnt(8)")
        PHASE(0, 1, ((void)0),                       "vmcnt(4)")
        PHASE(1, 0, ((void)0),                       "vmcnt(0)")
        PHASE(1, 1, ((void)0),                       "vmcnt(0)")
    }
#undef PHASE
#undef SA
#undef SB
#undef REGOFF

    // ---------------- epilogue ----------------
    const long cb = QKV ? 0 : (long)z * sC;
    const int row0 = tm * 256 + wr * 128 + (l >> 4) * 4;
    const int col0 = tn * 256 + wc * 64 + rl;

    if (QKV && gsel == 2) {
        // group 2 (U): write directly transposed as Ut[b][c'][m] (b=tm>>1,
        // m_base=(tm&1)*256); EPI0-style full-line NT read-back.
        float b4[4];
        #pragma unroll
        for (int n = 0; n < 4; ++n) b4[n] = bias[col0 + n * 16];
        unsigned short* vout = (unsigned short*)Cout;
        const int bz = tm >> 1, mb = (tm & 1) * 256;
        #pragma unroll
        for (int hc = 0; hc < 2; ++hc) {
            if ((wc >> 1) == hc) {
                #pragma unroll
                for (int mi = 0; mi < 8; ++mi)
                    #pragma unroll
                    for (int n = 0; n < 4; ++n)
                        #pragma unroll
                        for (int r = 0; r < 4; ++r) {
                            const int lc = (wc & 1) * 64 + n * 16 + rl;
                            const int m  = wr * 128 + mi * 16 + ((l >> 4) << 2) + r;
                            lds[lc * 264 + m] = f2bf(acc[mi][n][r] + b4[n]);
                        }
            }
            __syncthreads();
            #pragma unroll
            for (int rr = 0; rr < 8; ++rr) {
                const int row = rr * 16 + (tid >> 5);
                const int ch = tid & 31;
                short8 vv = *(const short8*)&lds[row * 264 + ch * 8];
                __builtin_nontemporal_store(vv,
                    (short8*)&vout[(size_t)bz * 655360
                        + (size_t)(tn * 256 + hc * 128 + row) * 512 + mb + ch * 8]);
            }
            __syncthreads();
        }
    } else if (EPI == 0) {
        float b4[4];
        #pragma unroll
        for (int n = 0; n < 4; ++n) b4[n] = bias[col0 + n * 16];
        unsigned short* gout = (unsigned short*)Cout;
        #pragma unroll
        for (int half = 0; half < 2; ++half) {
            if (wr == half) {
                #pragma unroll
                for (int mi = 0; mi < 8; ++mi)
                    #pragma unroll
                    for (int n = 0; n < 4; ++n)
                        #pragma unroll
                        for (int r = 0; r < 4; ++r) {
                            const int lr = mi * 16 + ((l >> 4) << 2) + r;
                            const int lc = wc * 64 + n * 16 + rl;
                            lds[lr * 264 + lc] = f2bf(acc[mi][n][r] + b4[n]);
                        }
            }
            __syncthreads();
            const long rbase = (long)(tm * 256 + half * 128);
            #pragma unroll
            for (int rr = 0; rr < 8; ++rr) {
                const int row = rr * 16 + (tid >> 5);
                const int ch = tid & 31;
                short8 vv = *(const short8*)&lds[row * 264 + ch * 8];
                __builtin_nontemporal_store(vv,
                    (short8*)&gout[(rbase + row) * (size_t)ldc + tn * 256 + ch * 8]);
            }
            __syncthreads();
        }
    } else {
        #pragma unroll
        for (int mi = 0; mi < 8; ++mi) {
            #pragma unroll
            for (int n = 0; n < 4; ++n) {
                #pragma unroll
                for (int r = 0; r < 4; ++r) {
                    const int row = row0 + mi * 16 + r;
                    const int col = col0 + n * 16;
                    float v = acc[mi][n][r];
                    if (EPI == 3) v += bias[col];
                    if (EPI == 3)
                        __builtin_nontemporal_store(v, &((float*)Cout)[cb + (long)row * ldc + col]);
                    else
                        ((unsigned short*)Cout)[cb + (long)row * ldc + col] = f2bf(v);
                }
            }
        }
    }
}

// ---------------------------------------------------------------------------
// Fused scores + masked softmax: Pt[b][n][m] (verified r14, 647us).
// ---------------------------------------------------------------------------
__global__ __launch_bounds__(512, 2) void qk_softmax(
    const unsigned short* __restrict__ Q, const unsigned short* __restrict__ Km,
    unsigned short* __restrict__ Pt, const int* __restrict__ mask, float scale)
{
    __shared__ unsigned short lds[65536];

    const unsigned gx = gridDim.x;
    unsigned lin = blockIdx.x + gx * blockIdx.z;
    const unsigned nwg = gx * gridDim.z;                // 256, %8==0
    lin = (lin & 7u) * (nwg >> 3) + (lin >> 3);
    const int tm = lin % gx;
    const int z  = lin / gx;

    const unsigned short* Ab = Q  + (size_t)z * 655360 + (size_t)(tm * 128) * 1280;
    const unsigned short* Bb = Km + (size_t)z * 655360;

    const int tid = threadIdx.x, wave = tid >> 6, l = tid & 63;
    const int wr = wave >> 2, wc = wave & 3;
    const int rl = l & 15, lh = l >> 4;

    const int schunk = ((l & 3) ^ ((l >> 3) & 3)) * 8;
    const unsigned short* agS = Ab + (size_t)(wave * 16 + (l >> 2)) * 1280 + schunk;
    const unsigned short* bgS = Bb + (size_t)(wave * 16 + (l >> 2)) * 1280 + schunk;
    unsigned short* ldsA = &lds[wave * 512];
    unsigned short* ldsB = &lds[4096 + wave * 512];

    const int cl8 = ((l >> 4) ^ ((l >> 1) & 3)) * 8;
    const int aoff = (wr * 64 + rl) * 32 + cl8;
    const int boff = 4096 + (wc * 128 + rl) * 32 + cl8;

#define SLOT(s) ((s) * 20480)
#define SAQ(t, s) { GLD16(agS + (size_t)(t) * 32, ldsA + SLOT(s)); }
#define SBQ(t, s) { const unsigned short* g_ = bgS + (size_t)(t) * 32; \
    GLD16(g_,                       ldsB + SLOT(s)); \
    GLD16(g_ + (size_t)128 * 1280,  ldsB + SLOT(s) + 4096); \
    GLD16(g_ + (size_t)256 * 1280,  ldsB + SLOT(s) + 8192); \
    GLD16(g_ + (size_t)384 * 1280,  ldsB + SLOT(s) + 12288); }

    f32x4 acc[4][8] = {};

    SAQ(0, 0) SBQ(0, 0) SAQ(1, 1) SBQ(1, 1)
    asm volatile("s_waitcnt vmcnt(5)" ::: "memory");
    __builtin_amdgcn_s_barrier();

    int g0 = 0;
    for (int t = 0; t < 40; ++t) {
        const int base = g0 * 20480;
        int g2 = g0 + 2; if (g2 >= 3) g2 -= 3;
        const bool stg = (t + 2 < 40);
        short8 af[4], bfv[8];
        #pragma unroll
        for (int i = 0; i < 4; ++i) af[i] = *(const short8*)&lds[base + aoff + i * 512];
        #pragma unroll
        for (int n = 0; n < 8; ++n) bfv[n] = *(const short8*)&lds[base + boff + n * 512];
        if (stg) { SAQ(t + 2, g2) SBQ(t + 2, g2) }
        __builtin_amdgcn_s_setprio(1);
        #pragma unroll
        for (int i = 0; i < 4; ++i)
            #pragma unroll
            for (int n = 0; n < 8; ++n)
                acc[i][n] = __builtin_amdgcn_mfma_f32_16x16x32_bf16(af[i], bfv[n], acc[i][n], 0, 0, 0);
        __builtin_amdgcn_s_setprio(0);
        if (stg) { asm volatile("s_waitcnt vmcnt(5)" ::: "memory"); }
        else     { asm volatile("s_waitcnt vmcnt(0)" ::: "memory"); }
        __builtin_amdgcn_s_barrier();
        g0 = (g0 == 2) ? 0 : g0 + 1;
    }
#undef SAQ
#undef SBQ
#undef SLOT

    const int col0 = wc * 128 + rl;
    {
        const int* mb = mask + (size_t)z * 262144;
        #pragma unroll
        for (int mi = 0; mi < 4; ++mi)
            #pragma unroll
            for (int r = 0; r < 4; ++r) {
                const int m = tm * 128 + wr * 64 + mi * 16 + lh * 4 + r;
                const int* mp = mb + (size_t)m * 512 + col0;
                #pragma unroll
                for (int nj = 0; nj < 8; ++nj) {
                    float x = acc[mi][nj][r] * scale;
                    if (mp[nj * 16] == 0) x = -2.795084971874737e18f;
                    acc[mi][nj][r] = x;
                }
            }
    }
    float* red = (float*)lds;
    float rmx[4][4], rinv[4][4];
    #pragma unroll
    for (int mi = 0; mi < 4; ++mi)
        #pragma unroll
        for (int r = 0; r < 4; ++r) {
            float mx = acc[mi][0][r];
            #pragma unroll
            for (int nj = 1; nj < 8; ++nj) mx = fmaxf(mx, acc[mi][nj][r]);
            mx = fmaxf(mx, __shfl_xor(mx, 1));
            mx = fmaxf(mx, __shfl_xor(mx, 2));
            mx = fmaxf(mx, __shfl_xor(mx, 4));
            mx = fmaxf(mx, __shfl_xor(mx, 8));
            if (rl == 0) red[wc * 128 + wr * 64 + mi * 16 + lh * 4 + r] = mx;
        }
    __syncthreads();
    #pragma unroll
    for (int mi = 0; mi < 4; ++mi)
        #pragma unroll
        for (int r = 0; r < 4; ++r) {
            const int rowl = wr * 64 + mi * 16 + lh * 4 + r;
            rmx[mi][r] = fmaxf(fmaxf(red[rowl], red[128 + rowl]),
                               fmaxf(red[256 + rowl], red[384 + rowl]));
        }
    __syncthreads();
    #pragma unroll
    for (int mi = 0; mi < 4; ++mi)
        #pragma unroll
        for (int r = 0; r < 4; ++r) {
            float s = 0.f;
            #pragma unroll
            for (int nj = 0; nj < 8; ++nj) {
                float e = __expf(acc[mi][nj][r] - rmx[mi][r]);
                acc[mi][nj][r] = e; s += e;
            }
            s += __shfl_xor(s, 1); s += __shfl_xor(s, 2);
            s += __shfl_xor(s, 4); s += __shfl_xor(s, 8);
            if (rl == 0) red[wc * 128 + wr * 64 + mi * 16 + lh * 4 + r] = s;
        }
    __syncthreads();
    #pragma unroll
    for (int mi = 0; mi < 4; ++mi)
        #pragma unroll
        for (int r = 0; r < 4; ++r) {
            const int rowl = wr * 64 + mi * 16 + lh * 4 + r;
            rinv[mi][r] = 1.0f / (red[rowl] + red[128 + rowl] + red[256 + rowl] + red[384 + rowl]);
        }
    unsigned short* Pb = Pt + (size_t)z * 262144 + (size_t)tm * 128;
    #pragma unroll
    for (int nh = 0; nh < 2; ++nh) {
        __syncthreads();
        if ((wc >> 1) == nh) {
            #pragma unroll
            for (int mi = 0; mi < 4; ++mi)
                #pragma unroll
                for (int nj = 0; nj < 8; ++nj)
                    #pragma unroll
                    for (int r = 0; r < 4; ++r) {
                        const int cl = (wc & 1) * 128 + nj * 16 + rl;
                        const int rowl = wr * 64 + mi * 16 + lh * 4 + r;
                        lds[cl * 132 + rowl] = f2bf(acc[mi][nj][r] * rinv[mi][r]);
                    }
        }
        __syncthreads();
        #pragma unroll
        for (int rr = 0; rr < 8; ++rr) {
            const int nl = rr * 32 + (tid >> 4);
            const int ch = tid & 15;
            short8 vv = *(const short8*)&lds[nl * 132 + ch * 8];
            *(short8*)&Pb[(size_t)(nh * 256 + nl) * 512 + ch * 8] = vv;
        }
    }
}

// ---------------------------------------------------------------------------
// transpose+cast Wq,Wk,Wr -> Wt slots 0,1,3 ([j][k] bf16); Wv -> straight
// bf16 cast into Wvb (for the Wvr = Wv.Wr precompute).
// ---------------------------------------------------------------------------
__global__ void transpose_w(const float* __restrict__ Wq, const float* __restrict__ Wk,
                            const float* __restrict__ Wv, const float* __restrict__ Wr,
                            unsigned short* __restrict__ Wt, unsigned short* __restrict__ Wvb)
{
    const float* W = blockIdx.z == 0 ? Wq : blockIdx.z == 1 ? Wk : blockIdx.z == 2 ? Wv : Wr;
    const int j0 = blockIdx.x * 64, k0 = blockIdx.y * 64;
    const int tid = threadIdx.x;
    if (blockIdx.z == 2) {       // straight cast Wv -> Wvb[k][c]
        for (int it = 0; it < 16; ++it) {
            int idx = it * 256 + tid;
            int r = idx >> 6, c = idx & 63;
            Wvb[(size_t)(k0 + r) * 1280 + j0 + c] = f2bf(W[(size_t)(k0 + r) * 1280 + j0 + c]);
        }
        return;
    }
    unsigned short* dst = Wt + (size_t)blockIdx.z * 1280 * 1280;
    __shared__ float T[64][65];
    for (int it = 0; it < 16; ++it) {
        int idx = it * 256 + tid;
        int r = idx >> 6, c = idx & 63;
        T[r][c] = W[(size_t)(k0 + r) * 1280 + j0 + c];
    }
    __syncthreads();
    for (int it = 0; it < 16; ++it) {
        int idx = it * 256 + tid;
        int r = idx >> 6, c = idx & 63;
        dst[(size_t)(j0 + r) * 1280 + k0 + c] = f2bf(T[c][r]);
    }
}

// bvr[c'] = sum_c bv[c] * Wr[c][c']   (f32; coalesced across the wave)
__global__ void bias_vr(const float* __restrict__ bv, const float* __restrict__ Wr,
                        float* __restrict__ bvr)
{
    const int cp = blockIdx.x * 256 + threadIdx.x;
    float s = 0.f;
    for (int c = 0; c < 1280; ++c) s += bv[c] * Wr[(size_t)c * 1280 + cp];
    bvr[cp] = s;
}

// ---------------------------------------------------------------------------
// Cast x f32 -> bf16, vectorized
// ---------------------------------------------------------------------------
__global__ void cast_x(const float* __restrict__ x, unsigned short* __restrict__ xb, long n)
{
    long i = ((long)blockIdx.x * 256 + threadIdx.x) * 8;
    if (i + 8 > n) return;
    const float4* p = (const float4*)(x + i);
    float4 a = p[0], b = p[1];
    unsigned short o[8] = { f2bf(a.x), f2bf(a.y), f2bf(a.z), f2bf(a.w),
                            f2bf(b.x), f2bf(b.y), f2bf(b.z), f2bf(b.w) };
    *(short8*)(xb + i) = *(short8*)o;
}

// ---------------------------------------------------------------------------
extern "C" void kernel_launch(void* const* d_in, const int* in_sizes, int n_in,
                              void* d_out, int out_size, void* d_ws, size_t ws_size,
                              hipStream_t stream)
{
    const float* x   = (const float*)d_in[0];
    const int*  Mask = (const int*)d_in[1];
    const float* Wq  = (const float*)d_in[2];
    const float* bq  = (const float*)d_in[3];
    const float* Wk  = (const float*)d_in[4];
    const float* bk  = (const float*)d_in[5];
    const float* Wv  = (const float*)d_in[6];
    const float* bv  = (const float*)d_in[7];
    const float* Wr  = (const float*)d_in[8];
    const float* br  = (const float*)d_in[9];

    constexpr int N = 512, C = 1280;
    constexpr long MN = 32768;   // B*N

    char* ws = (char*)d_ws;
    unsigned short* xb  = (unsigned short*)ws;                          // 83886080 B
    unsigned short* Wt  = (unsigned short*)(ws + 83886080);             // 4 slots, 13107200 B
    unsigned short* Wvb = (unsigned short*)(ws + 96993280);             // 3276800 B
    float*          bvr = (float*)(ws + 100270080);                     // 5120 B
    unsigned short* Q   = (unsigned short*)(ws + 100278272);            // MN*C
    unsigned short* Km  = Q + 41943040;
    unsigned short* Ut  = Km + 41943040;                                // Ut[b][c'][m]
    unsigned short* Pt  = Ut + 41943040;                                // B*N*N

    const float scale = 0.02795084971874737f;   // 1/sqrt(1280)

    transpose_w<<<dim3(20, 20, 4), 256, 0, stream>>>(Wq, Wk, Wv, Wr, Wt, Wvb);

    // Wvrt = (Wv.Wr)^T into Wt slot 2:  C[i][j] = sum_k Wrt[i][k]*Wvb[j][k]
    gemm256<2, 0><<<dim3(5, 5, 1), 512, 0, stream>>>(Wt + 3 * 1638400, Wvb,
        (void*)(Wt + 2 * 1638400), nullptr, nullptr, nullptr,
        C, C, C, C, 0, 0, 0, 0);

    bias_vr<<<dim3(5), 256, 0, stream>>>(bv, Wr, bvr);

    cast_x<<<dim3(20480), 256, 0, stream>>>(x, xb, MN * C);

    // fused Q/K/U projections: M=32768, N=3x1280, K=1280; tn/5 selects group.
    // group 2 = U = x.Wvr + bvr, written transposed into Ut.
    gemm256<0, 1><<<dim3(15, 128, 1), 512, 0, stream>>>(xb, Wt, (void*)Q, bq, bk, bvr,
        C, C, C, C, 0, 1638400L, 41943040L, 1);

    // fused scores+softmax: Pt[b][n][m] = softmax(scale*Q.K^T, mask)
    qk_softmax<<<dim3(4, 1, 64), 512, 0, stream>>>(Q, Km, Pt, Mask, scale);

    // out[b][n][c'] = sum_m Pt[b][n][m] * Ut[b][c'][m] + br  (f32, final)
    gemm256<3, 0><<<dim3(5, 2, 64), 512, 0, stream>>>(Pt, Ut, d_out, br, nullptr, nullptr,
        N, N, N, C, (long)N * N, (long)C * N, (long)N * C, 1);
}

// Round 16
// 655.041 us; speedup vs baseline: 1.0119x; 1.0119x over previous
//
#include <hip/hip_runtime.h>
#include <hip/hip_bf16.h>

#define DI __device__ __forceinline__

typedef __attribute__((ext_vector_type(8))) short short8;
typedef __attribute__((ext_vector_type(4))) float f32x4;

DI unsigned short f2bf(float f) {
    union { float f; unsigned int u; } v; v.f = f;
    unsigned int r = v.u + 0x7FFFu + ((v.u >> 16) & 1u);
    return (unsigned short)(r >> 16);
}
DI float bf2f(unsigned short h) {
    union { unsigned int u; float f; } v; v.u = ((unsigned int)h) << 16;
    return v.f;
}

#define GLD16(g, l) __builtin_amdgcn_global_load_lds( \
    (const __attribute__((address_space(1))) void*)(g), \
    (__attribute__((address_space(3))) void*)(l), 16, 0, 0)

// ---------------------------------------------------------------------------
// 256x256 4-phase NT GEMM, BK=64, 8 waves (2Mx4N), 128KiB LDS.  (r13 core.)
// C[i][j] = sum_k A[i][k] * Bt[j][k]
// Swizzle LDS[r][p] = G[r][p ^ ((r>>1)&3)] (conflict-free).  XCD chunking
// (bijective, requires nwg%8==0 -> gated by doswz).  NT full-line stores.
// QKV group 2 writes output directly transposed ([b][col][m]) -> Ut.
// EPI: 0 = +bias->bf16(NT), 2 = bf16, 3 = +bias->f32(NT),
//      4 = f32 partial (split-K chunk z -> Cout + z*sC, cached stores)
// ---------------------------------------------------------------------------
template<int EPI, int QKV>
__global__ __launch_bounds__(512, 2) void gemm256(
    const unsigned short* __restrict__ A, const unsigned short* __restrict__ Bt,
    void* __restrict__ Cout, const float* __restrict__ bias,
    const float* __restrict__ bias1, const float* __restrict__ bias2,
    int K, int lda, int ldb, int ldc,
    long sA, long sB, long sC, int doswz)
{
    __shared__ unsigned short lds[65536];   // 128 KiB

    const unsigned gx = gridDim.x, gy = gridDim.y;
    unsigned lin = blockIdx.x + gx * (blockIdx.y + gy * blockIdx.z);
    if (doswz) {
        const unsigned nwg = gx * gy * gridDim.z;   // must be %8==0
        lin = (lin & 7u) * (nwg >> 3) + (lin >> 3);
    }
    int tn = lin % gx;
    const int tm = (lin / gx) % gy;
    const int z = lin / (gx * gy);

    int gsel = 0;
    if (QKV) {
        gsel = tn / 5; tn -= gsel * 5;
        Bt += (size_t)gsel * sB;
        Cout = (void*)((unsigned short*)Cout + (size_t)gsel * sC);
        if (gsel == 1) bias = bias1; else if (gsel == 2) bias = bias2;
    }

    const unsigned short* Ab = A + (QKV ? 0 : (long)z * sA) + (size_t)(tm * 256) * lda;
    const unsigned short* Bb = Bt + (QKV ? 0 : (long)z * sB) + (size_t)(tn * 256) * ldb;

    const int tid = threadIdx.x, wave = tid >> 6, l = tid & 63;
    const int wr = wave >> 2, wc = wave & 3;    // 2 x 4 wave grid

    const int srow = wave * 32 + (l >> 2);
    const int schunk = ((l & 3) ^ ((l >> 3) & 3)) * 8;
    const unsigned short* agS = Ab + (size_t)srow * lda + schunk;
    const unsigned short* bgS = Bb + (size_t)srow * ldb + schunk;
    unsigned short* ldsA0 = &lds[wave * 1024];
    unsigned short* ldsB0 = &lds[8192 + wave * 1024];

    const int rl = l & 15;
    const int cl8 = ((l >> 4) ^ ((l >> 1) & 3)) * 8;
    const int aoff = (wr * 128 + rl) * 32 + cl8;
    const int boff = 8192 + (wc * 64 + rl) * 32 + cl8;

#define REGOFF(buf, h) (((buf) * 2 + (h)) * 16384)
#define SA(t, h, buf) { const unsigned short* g_ = agS + (size_t)((t) * 64 + (h) * 32); \
    GLD16(g_, ldsA0 + REGOFF(buf, h)); \
    GLD16(g_ + (size_t)16 * lda, ldsA0 + REGOFF(buf, h) + 512); }
#define SB(t, h, buf) { const unsigned short* g_ = bgS + (size_t)((t) * 64 + (h) * 32); \
    GLD16(g_, ldsB0 + REGOFF(buf, h)); \
    GLD16(g_ + (size_t)16 * ldb, ldsB0 + REGOFF(buf, h) + 512); }

    f32x4 acc[8][4] = {};

#define PHASE(buf, h, STG, VMW) { \
    short8 af[8], bfv[4]; \
    _Pragma("unroll") for (int i = 0; i < 4; ++i) \
        af[i] = *(const short8*)&lds[REGOFF(buf, h) + aoff + i * 512]; \
    _Pragma("unroll") for (int n = 0; n < 4; ++n) \
        bfv[n] = *(const short8*)&lds[REGOFF(buf, h) + boff + n * 512]; \
    _Pragma("unroll") for (int i = 4; i < 8; ++i) \
        af[i] = *(const short8*)&lds[REGOFF(buf, h) + aoff + i * 512]; \
    STG; \
    __builtin_amdgcn_s_setprio(1); \
    _Pragma("unroll") for (int i = 0; i < 8; ++i) \
        _Pragma("unroll") for (int n = 0; n < 4; ++n) \
            acc[i][n] = __builtin_amdgcn_mfma_f32_16x16x32_bf16( \
                af[i], bfv[n], acc[i][n], 0, 0, 0); \
    __builtin_amdgcn_s_setprio(0); \
    asm volatile("s_waitcnt " VMW ::: "memory"); \
    __builtin_amdgcn_s_barrier(); \
  }

    SA(0, 0, 0); SB(0, 0, 0); SA(0, 1, 0); SB(0, 1, 0); SA(1, 0, 1); SB(1, 0, 1);
    asm volatile("s_waitcnt vmcnt(8)" ::: "memory");
    __builtin_amdgcn_s_barrier();

    const int NI = K >> 7;
    for (int j = 0; j < NI - 1; ++j) {
        const int t = 2 * j;
        PHASE(0, 0, SA(t + 1, 1, 1) SB(t + 1, 1, 1), "vmcnt(8)")
        PHASE(0, 1, SA(t + 2, 0, 0) SB(t + 2, 0, 0), "vmcnt(8)")
        PHASE(1, 0, SA(t + 2, 1, 0) SB(t + 2, 1, 0), "vmcnt(8)")
        PHASE(1, 1, SA(t + 3, 0, 1) SB(t + 3, 0, 1), "vmcnt(8)")
    }
    {
        const int t = 2 * (NI - 1);
        PHASE(0, 0, SA(t + 1, 1, 1) SB(t + 1, 1, 1), "vmcnt(8)")
        PHASE(0, 1, ((void)0),                       "vmcnt(4)")
        PHASE(1, 0, ((void)0),                       "vmcnt(0)")
        PHASE(1, 1, ((void)0),                       "vmcnt(0)")
    }
#undef PHASE
#undef SA
#undef SB
#undef REGOFF

    // ---------------- epilogue ----------------
    const long cb = QKV ? 0 : (long)z * sC;
    const int row0 = tm * 256 + wr * 128 + (l >> 4) * 4;
    const int col0 = tn * 256 + wc * 64 + rl;

    if (QKV && gsel == 2) {
        // group 2 (U): write directly transposed as Ut[b][c'][m]
        float b4[4];
        #pragma unroll
        for (int n = 0; n < 4; ++n) b4[n] = bias[col0 + n * 16];
        unsigned short* vout = (unsigned short*)Cout;
        const int bz = tm >> 1, mb = (tm & 1) * 256;
        #pragma unroll
        for (int hc = 0; hc < 2; ++hc) {
            if ((wc >> 1) == hc) {
                #pragma unroll
                for (int mi = 0; mi < 8; ++mi)
                    #pragma unroll
                    for (int n = 0; n < 4; ++n)
                        #pragma unroll
                        for (int r = 0; r < 4; ++r) {
                            const int lc = (wc & 1) * 64 + n * 16 + rl;
                            const int m  = wr * 128 + mi * 16 + ((l >> 4) << 2) + r;
                            lds[lc * 264 + m] = f2bf(acc[mi][n][r] + b4[n]);
                        }
            }
            __syncthreads();
            #pragma unroll
            for (int rr = 0; rr < 8; ++rr) {
                const int row = rr * 16 + (tid >> 5);
                const int ch = tid & 31;
                short8 vv = *(const short8*)&lds[row * 264 + ch * 8];
                __builtin_nontemporal_store(vv,
                    (short8*)&vout[(size_t)bz * 655360
                        + (size_t)(tn * 256 + hc * 128 + row) * 512 + mb + ch * 8]);
            }
            __syncthreads();
        }
    } else if (EPI == 0) {
        float b4[4];
        #pragma unroll
        for (int n = 0; n < 4; ++n) b4[n] = bias[col0 + n * 16];
        unsigned short* gout = (unsigned short*)Cout;
        #pragma unroll
        for (int half = 0; half < 2; ++half) {
            if (wr == half) {
                #pragma unroll
                for (int mi = 0; mi < 8; ++mi)
                    #pragma unroll
                    for (int n = 0; n < 4; ++n)
                        #pragma unroll
                        for (int r = 0; r < 4; ++r) {
                            const int lr = mi * 16 + ((l >> 4) << 2) + r;
                            const int lc = wc * 64 + n * 16 + rl;
                            lds[lr * 264 + lc] = f2bf(acc[mi][n][r] + b4[n]);
                        }
            }
            __syncthreads();
            const long rbase = (long)(tm * 256 + half * 128);
            #pragma unroll
            for (int rr = 0; rr < 8; ++rr) {
                const int row = rr * 16 + (tid >> 5);
                const int ch = tid & 31;
                short8 vv = *(const short8*)&lds[row * 264 + ch * 8];
                __builtin_nontemporal_store(vv,
                    (short8*)&gout[(rbase + row) * (size_t)ldc + tn * 256 + ch * 8]);
            }
            __syncthreads();
        }
    } else {
        #pragma unroll
        for (int mi = 0; mi < 8; ++mi) {
            #pragma unroll
            for (int n = 0; n < 4; ++n) {
                #pragma unroll
                for (int r = 0; r < 4; ++r) {
                    const int row = row0 + mi * 16 + r;
                    const int col = col0 + n * 16;
                    float v = acc[mi][n][r];
                    if (EPI == 3) v += bias[col];
                    if (EPI == 3)
                        __builtin_nontemporal_store(v, &((float*)Cout)[cb + (long)row * ldc + col]);
                    else if (EPI == 4)   // split-K partial: cached f32
                        ((float*)Cout)[cb + (long)row * ldc + col] = v;
                    else
                        ((unsigned short*)Cout)[cb + (long)row * ldc + col] = f2bf(v);
                }
            }
        }
    }
}

// ---------------------------------------------------------------------------
// Fused scores + masked softmax: Pt[b][n][m] (verified r14, 647us).
// ---------------------------------------------------------------------------
__global__ __launch_bounds__(512, 2) void qk_softmax(
    const unsigned short* __restrict__ Q, const unsigned short* __restrict__ Km,
    unsigned short* __restrict__ Pt, const int* __restrict__ mask, float scale)
{
    __shared__ unsigned short lds[65536];

    const unsigned gx = gridDim.x;
    unsigned lin = blockIdx.x + gx * blockIdx.z;
    const unsigned nwg = gx * gridDim.z;                // 256, %8==0
    lin = (lin & 7u) * (nwg >> 3) + (lin >> 3);
    const int tm = lin % gx;
    const int z  = lin / gx;

    const unsigned short* Ab = Q  + (size_t)z * 655360 + (size_t)(tm * 128) * 1280;
    const unsigned short* Bb = Km + (size_t)z * 655360;

    const int tid = threadIdx.x, wave = tid >> 6, l = tid & 63;
    const int wr = wave >> 2, wc = wave & 3;
    const int rl = l & 15, lh = l >> 4;

    const int schunk = ((l & 3) ^ ((l >> 3) & 3)) * 8;
    const unsigned short* agS = Ab + (size_t)(wave * 16 + (l >> 2)) * 1280 + schunk;
    const unsigned short* bgS = Bb + (size_t)(wave * 16 + (l >> 2)) * 1280 + schunk;
    unsigned short* ldsA = &lds[wave * 512];
    unsigned short* ldsB = &lds[4096 + wave * 512];

    const int cl8 = ((l >> 4) ^ ((l >> 1) & 3)) * 8;
    const int aoff = (wr * 64 + rl) * 32 + cl8;
    const int boff = 4096 + (wc * 128 + rl) * 32 + cl8;

#define SLOT(s) ((s) * 20480)
#define SAQ(t, s) { GLD16(agS + (size_t)(t) * 32, ldsA + SLOT(s)); }
#define SBQ(t, s) { const unsigned short* g_ = bgS + (size_t)(t) * 32; \
    GLD16(g_,                       ldsB + SLOT(s)); \
    GLD16(g_ + (size_t)128 * 1280,  ldsB + SLOT(s) + 4096); \
    GLD16(g_ + (size_t)256 * 1280,  ldsB + SLOT(s) + 8192); \
    GLD16(g_ + (size_t)384 * 1280,  ldsB + SLOT(s) + 12288); }

    f32x4 acc[4][8] = {};

    SAQ(0, 0) SBQ(0, 0) SAQ(1, 1) SBQ(1, 1)
    asm volatile("s_waitcnt vmcnt(5)" ::: "memory");
    __builtin_amdgcn_s_barrier();

    int g0 = 0;
    for (int t = 0; t < 40; ++t) {
        const int base = g0 * 20480;
        int g2 = g0 + 2; if (g2 >= 3) g2 -= 3;
        const bool stg = (t + 2 < 40);
        short8 af[4], bfv[8];
        #pragma unroll
        for (int i = 0; i < 4; ++i) af[i] = *(const short8*)&lds[base + aoff + i * 512];
        #pragma unroll
        for (int n = 0; n < 8; ++n) bfv[n] = *(const short8*)&lds[base + boff + n * 512];
        if (stg) { SAQ(t + 2, g2) SBQ(t + 2, g2) }
        __builtin_amdgcn_s_setprio(1);
        #pragma unroll
        for (int i = 0; i < 4; ++i)
            #pragma unroll
            for (int n = 0; n < 8; ++n)
                acc[i][n] = __builtin_amdgcn_mfma_f32_16x16x32_bf16(af[i], bfv[n], acc[i][n], 0, 0, 0);
        __builtin_amdgcn_s_setprio(0);
        if (stg) { asm volatile("s_waitcnt vmcnt(5)" ::: "memory"); }
        else     { asm volatile("s_waitcnt vmcnt(0)" ::: "memory"); }
        __builtin_amdgcn_s_barrier();
        g0 = (g0 == 2) ? 0 : g0 + 1;
    }
#undef SAQ
#undef SBQ
#undef SLOT

    const int col0 = wc * 128 + rl;
    {
        const int* mb = mask + (size_t)z * 262144;
        #pragma unroll
        for (int mi = 0; mi < 4; ++mi)
            #pragma unroll
            for (int r = 0; r < 4; ++r) {
                const int m = tm * 128 + wr * 64 + mi * 16 + lh * 4 + r;
                const int* mp = mb + (size_t)m * 512 + col0;
                #pragma unroll
                for (int nj = 0; nj < 8; ++nj) {
                    float x = acc[mi][nj][r] * scale;
                    if (mp[nj * 16] == 0) x = -2.795084971874737e18f;
                    acc[mi][nj][r] = x;
                }
            }
    }
    float* red = (float*)lds;
    float rmx[4][4], rinv[4][4];
    #pragma unroll
    for (int mi = 0; mi < 4; ++mi)
        #pragma unroll
        for (int r = 0; r < 4; ++r) {
            float mx = acc[mi][0][r];
            #pragma unroll
            for (int nj = 1; nj < 8; ++nj) mx = fmaxf(mx, acc[mi][nj][r]);
            mx = fmaxf(mx, __shfl_xor(mx, 1));
            mx = fmaxf(mx, __shfl_xor(mx, 2));
            mx = fmaxf(mx, __shfl_xor(mx, 4));
            mx = fmaxf(mx, __shfl_xor(mx, 8));
            if (rl == 0) red[wc * 128 + wr * 64 + mi * 16 + lh * 4 + r] = mx;
        }
    __syncthreads();
    #pragma unroll
    for (int mi = 0; mi < 4; ++mi)
        #pragma unroll
        for (int r = 0; r < 4; ++r) {
            const int rowl = wr * 64 + mi * 16 + lh * 4 + r;
            rmx[mi][r] = fmaxf(fmaxf(red[rowl], red[128 + rowl]),
                               fmaxf(red[256 + rowl], red[384 + rowl]));
        }
    __syncthreads();
    #pragma unroll
    for (int mi = 0; mi < 4; ++mi)
        #pragma unroll
        for (int r = 0; r < 4; ++r) {
            float s = 0.f;
            #pragma unroll
            for (int nj = 0; nj < 8; ++nj) {
                float e = __expf(acc[mi][nj][r] - rmx[mi][r]);
                acc[mi][nj][r] = e; s += e;
            }
            s += __shfl_xor(s, 1); s += __shfl_xor(s, 2);
            s += __shfl_xor(s, 4); s += __shfl_xor(s, 8);
            if (rl == 0) red[wc * 128 + wr * 64 + mi * 16 + lh * 4 + r] = s;
        }
    __syncthreads();
    #pragma unroll
    for (int mi = 0; mi < 4; ++mi)
        #pragma unroll
        for (int r = 0; r < 4; ++r) {
            const int rowl = wr * 64 + mi * 16 + lh * 4 + r;
            rinv[mi][r] = 1.0f / (red[rowl] + red[128 + rowl] + red[256 + rowl] + red[384 + rowl]);
        }
    unsigned short* Pb = Pt + (size_t)z * 262144 + (size_t)tm * 128;
    #pragma unroll
    for (int nh = 0; nh < 2; ++nh) {
        __syncthreads();
        if ((wc >> 1) == nh) {
            #pragma unroll
            for (int mi = 0; mi < 4; ++mi)
                #pragma unroll
                for (int nj = 0; nj < 8; ++nj)
                    #pragma unroll
                    for (int r = 0; r < 4; ++r) {
                        const int cl = (wc & 1) * 128 + nj * 16 + rl;
                        const int rowl = wr * 64 + mi * 16 + lh * 4 + r;
                        lds[cl * 132 + rowl] = f2bf(acc[mi][nj][r] * rinv[mi][r]);
                    }
        }
        __syncthreads();
        #pragma unroll
        for (int rr = 0; rr < 8; ++rr) {
            const int nl = rr * 32 + (tid >> 4);
            const int ch = tid & 15;
            short8 vv = *(const short8*)&lds[nl * 132 + ch * 8];
            *(short8*)&Pb[(size_t)(nh * 256 + nl) * 512 + ch * 8] = vv;
        }
    }
}

// ---------------------------------------------------------------------------
// transpose+cast Wq,Wk,Wr -> Wt slots 0,1,3 ([j][k] bf16); Wv -> straight
// bf16 cast into Wvb (for the split-K Wvr = Wv.Wr precompute).
// ---------------------------------------------------------------------------
__global__ void transpose_w(const float* __restrict__ Wq, const float* __restrict__ Wk,
                            const float* __restrict__ Wv, const float* __restrict__ Wr,
                            unsigned short* __restrict__ Wt, unsigned short* __restrict__ Wvb)
{
    const float* W = blockIdx.z == 0 ? Wq : blockIdx.z == 1 ? Wk : blockIdx.z == 2 ? Wv : Wr;
    const int j0 = blockIdx.x * 64, k0 = blockIdx.y * 64;
    const int tid = threadIdx.x;
    if (blockIdx.z == 2) {       // straight cast Wv -> Wvb[k][c]
        for (int it = 0; it < 16; ++it) {
            int idx = it * 256 + tid;
            int r = idx >> 6, c = idx & 63;
            Wvb[(size_t)(k0 + r) * 1280 + j0 + c] = f2bf(W[(size_t)(k0 + r) * 1280 + j0 + c]);
        }
        return;
    }
    unsigned short* dst = Wt + (size_t)blockIdx.z * 1280 * 1280;
    __shared__ float T[64][65];
    for (int it = 0; it < 16; ++it) {
        int idx = it * 256 + tid;
        int r = idx >> 6, c = idx & 63;
        T[r][c] = W[(size_t)(k0 + r) * 1280 + j0 + c];
    }
    __syncthreads();
    for (int it = 0; it < 16; ++it) {
        int idx = it * 256 + tid;
        int r = idx >> 6, c = idx & 63;
        dst[(size_t)(j0 + r) * 1280 + k0 + c] = f2bf(T[c][r]);
    }
}

// ---------------------------------------------------------------------------
// Reduce the 5 split-K partials -> Wvrt bf16 (blocks 0..799); tail blocks
// (800..804) compute bvr[c'] = sum_c bv[c]*Wr[c][c'].
// ---------------------------------------------------------------------------
__global__ void reduce_wvr(const float* __restrict__ P, unsigned short* __restrict__ Wvrt,
                           const float* __restrict__ bv, const float* __restrict__ Wr,
                           float* __restrict__ bvr)
{
    const int bid = blockIdx.x;
    if (bid >= 800) {
        const int cp = (bid - 800) * 256 + threadIdx.x;
        float s = 0.f;
        for (int c = 0; c < 1280; ++c) s += bv[c] * Wr[(size_t)c * 1280 + cp];
        bvr[cp] = s;
        return;
    }
    const long i = ((long)bid * 256 + threadIdx.x) * 8;
    unsigned short o[8];
    #pragma unroll
    for (int j = 0; j < 8; ++j) {
        float s = P[i + j] + P[1638400 + i + j] + P[2 * 1638400 + i + j]
                + P[3 * 1638400 + i + j] + P[4 * 1638400 + i + j];
        o[j] = f2bf(s);
    }
    *(short8*)&Wvrt[i] = *(short8*)o;
}

// ---------------------------------------------------------------------------
// Cast x f32 -> bf16, vectorized
// ---------------------------------------------------------------------------
__global__ void cast_x(const float* __restrict__ x, unsigned short* __restrict__ xb, long n)
{
    long i = ((long)blockIdx.x * 256 + threadIdx.x) * 8;
    if (i + 8 > n) return;
    const float4* p = (const float4*)(x + i);
    float4 a = p[0], b = p[1];
    unsigned short o[8] = { f2bf(a.x), f2bf(a.y), f2bf(a.z), f2bf(a.w),
                            f2bf(b.x), f2bf(b.y), f2bf(b.z), f2bf(b.w) };
    *(short8*)(xb + i) = *(short8*)o;
}

// ---------------------------------------------------------------------------
extern "C" void kernel_launch(void* const* d_in, const int* in_sizes, int n_in,
                              void* d_out, int out_size, void* d_ws, size_t ws_size,
                              hipStream_t stream)
{
    const float* x   = (const float*)d_in[0];
    const int*  Mask = (const int*)d_in[1];
    const float* Wq  = (const float*)d_in[2];
    const float* bq  = (const float*)d_in[3];
    const float* Wk  = (const float*)d_in[4];
    const float* bk  = (const float*)d_in[5];
    const float* Wv  = (const float*)d_in[6];
    const float* bv  = (const float*)d_in[7];
    const float* Wr  = (const float*)d_in[8];
    const float* br  = (const float*)d_in[9];

    constexpr int N = 512, C = 1280;
    constexpr long MN = 32768;   // B*N

    char* ws = (char*)d_ws;
    unsigned short* xb  = (unsigned short*)ws;                          // 83886080 B
    unsigned short* Wt  = (unsigned short*)(ws + 83886080);             // 4 slots, 13107200 B
    unsigned short* Wvb = (unsigned short*)(ws + 96993280);             // 3276800 B
    float*          bvr = (float*)(ws + 100270080);                     // 5120 B
    float*          Pws = (float*)(ws + 100278272);                     // 5*1638400 f32 = 32768000 B
    unsigned short* Q   = (unsigned short*)(ws + 133046272);            // MN*C
    unsigned short* Km  = Q + 41943040;
    unsigned short* Ut  = Km + 41943040;                                // Ut[b][c'][m]
    unsigned short* Pt  = Ut + 41943040;                                // B*N*N

    const float scale = 0.02795084971874737f;   // 1/sqrt(1280)

    transpose_w<<<dim3(20, 20, 4), 256, 0, stream>>>(Wq, Wk, Wv, Wr, Wt, Wvb);

    // split-K Wvrt partials: chunk z computes K in [z*256,(z+1)*256)
    gemm256<4, 0><<<dim3(5, 5, 5), 512, 0, stream>>>(Wt + 3 * 1638400, Wvb,
        (void*)Pws, nullptr, nullptr, nullptr,
        256, C, C, C, 256L, 256L, 1638400L, 0);

    // reduce partials -> Wt slot 2 (bf16); tail blocks compute bvr
    reduce_wvr<<<dim3(805), 256, 0, stream>>>(Pws, Wt + 2 * 1638400, bv, Wr, bvr);

    cast_x<<<dim3(20480), 256, 0, stream>>>(x, xb, MN * C);

    // fused Q/K/U projections: group 2 = U = x.Wvr + bvr, written transposed.
    gemm256<0, 1><<<dim3(15, 128, 1), 512, 0, stream>>>(xb, Wt, (void*)Q, bq, bk, bvr,
        C, C, C, C, 0, 1638400L, 41943040L, 1);

    // fused scores+softmax: Pt[b][n][m] = softmax(scale*Q.K^T, mask)
    qk_softmax<<<dim3(4, 1, 64), 512, 0, stream>>>(Q, Km, Pt, Mask, scale);

    // out[b][n][c'] = sum_m Pt[b][n][m] * Ut[b][c'][m] + br  (f32, final)
    gemm256<3, 0><<<dim3(5, 2, 64), 512, 0, stream>>>(Pt, Ut, d_out, br, nullptr, nullptr,
        N, N, N, C, (long)N * N, (long)C * N, (long)N * C, 1);
}

// Round 17
// 644.414 us; speedup vs baseline: 1.0286x; 1.0165x over previous
//
#include <hip/hip_runtime.h>
#include <hip/hip_bf16.h>

#define DI __device__ __forceinline__

typedef __attribute__((ext_vector_type(8))) short short8;
typedef __attribute__((ext_vector_type(4))) float f32x4;

DI unsigned short f2bf(float f) {
    union { float f; unsigned int u; } v; v.f = f;
    unsigned int r = v.u + 0x7FFFu + ((v.u >> 16) & 1u);
    return (unsigned short)(r >> 16);
}
DI float bf2f(unsigned short h) {
    union { unsigned int u; float f; } v; v.u = ((unsigned int)h) << 16;
    return v.f;
}

#define GLD16(g, l) __builtin_amdgcn_global_load_lds( \
    (const __attribute__((address_space(1))) void*)(g), \
    (__attribute__((address_space(3))) void*)(l), 16, 0, 0)

// ---------------------------------------------------------------------------
// 256x256 4-phase NT GEMM, BK=64, 8 waves (2Mx4N), 128KiB LDS.  (r13 core,
// verified best.)  C[i][j] = sum_k A[i][k] * Bt[j][k]
// Swizzle LDS[r][p] = G[r][p ^ ((r>>1)&3)] (conflict-free).  XCD chunking
// (bijective, nwg%8==0).  NT full-line stores for write-once outputs.
// QKV group 2 (V) writes output directly transposed as Vt[b][c][m].
// EPI: 0 = +bias->bf16(NT), 2 = bf16, 3 = +bias->f32(NT)
// ---------------------------------------------------------------------------
template<int EPI, int QKV>
__global__ __launch_bounds__(512, 2) void gemm256(
    const unsigned short* __restrict__ A, const unsigned short* __restrict__ Bt,
    void* __restrict__ Cout, const float* __restrict__ bias,
    const float* __restrict__ bias1, const float* __restrict__ bias2,
    int K, int lda, int ldb, int ldc,
    long sA, long sB, long sC)
{
    __shared__ unsigned short lds[65536];   // 128 KiB

    const unsigned gx = gridDim.x, gy = gridDim.y;
    unsigned lin = blockIdx.x + gx * (blockIdx.y + gy * blockIdx.z);
    const unsigned nwg = gx * gy * gridDim.z;
    lin = (lin & 7u) * (nwg >> 3) + (lin >> 3);
    int tn = lin % gx;
    const int tm = (lin / gx) % gy;
    const int z = lin / (gx * gy);

    int gsel = 0;
    if (QKV) {
        gsel = tn / 5; tn -= gsel * 5;
        Bt += (size_t)gsel * sB;
        Cout = (void*)((unsigned short*)Cout + (size_t)gsel * sC);
        if (gsel == 1) bias = bias1; else if (gsel == 2) bias = bias2;
    }

    const unsigned short* Ab = A + (long)z * sA + (size_t)(tm * 256) * lda;
    const unsigned short* Bb = Bt + (QKV ? 0 : (long)z * sB) + (size_t)(tn * 256) * ldb;

    const int tid = threadIdx.x, wave = tid >> 6, l = tid & 63;
    const int wr = wave >> 2, wc = wave & 3;    // 2 x 4 wave grid

    const int srow = wave * 32 + (l >> 2);
    const int schunk = ((l & 3) ^ ((l >> 3) & 3)) * 8;
    const unsigned short* agS = Ab + (size_t)srow * lda + schunk;
    const unsigned short* bgS = Bb + (size_t)srow * ldb + schunk;
    unsigned short* ldsA0 = &lds[wave * 1024];
    unsigned short* ldsB0 = &lds[8192 + wave * 1024];

    const int rl = l & 15;
    const int cl8 = ((l >> 4) ^ ((l >> 1) & 3)) * 8;
    const int aoff = (wr * 128 + rl) * 32 + cl8;
    const int boff = 8192 + (wc * 64 + rl) * 32 + cl8;

#define REGOFF(buf, h) (((buf) * 2 + (h)) * 16384)
#define SA(t, h, buf) { const unsigned short* g_ = agS + (size_t)((t) * 64 + (h) * 32); \
    GLD16(g_, ldsA0 + REGOFF(buf, h)); \
    GLD16(g_ + (size_t)16 * lda, ldsA0 + REGOFF(buf, h) + 512); }
#define SB(t, h, buf) { const unsigned short* g_ = bgS + (size_t)((t) * 64 + (h) * 32); \
    GLD16(g_, ldsB0 + REGOFF(buf, h)); \
    GLD16(g_ + (size_t)16 * ldb, ldsB0 + REGOFF(buf, h) + 512); }

    f32x4 acc[8][4] = {};

#define PHASE(buf, h, STG, VMW) { \
    short8 af[8], bfv[4]; \
    _Pragma("unroll") for (int i = 0; i < 4; ++i) \
        af[i] = *(const short8*)&lds[REGOFF(buf, h) + aoff + i * 512]; \
    _Pragma("unroll") for (int n = 0; n < 4; ++n) \
        bfv[n] = *(const short8*)&lds[REGOFF(buf, h) + boff + n * 512]; \
    _Pragma("unroll") for (int i = 4; i < 8; ++i) \
        af[i] = *(const short8*)&lds[REGOFF(buf, h) + aoff + i * 512]; \
    STG; \
    __builtin_amdgcn_s_setprio(1); \
    _Pragma("unroll") for (int i = 0; i < 8; ++i) \
        _Pragma("unroll") for (int n = 0; n < 4; ++n) \
            acc[i][n] = __builtin_amdgcn_mfma_f32_16x16x32_bf16( \
                af[i], bfv[n], acc[i][n], 0, 0, 0); \
    __builtin_amdgcn_s_setprio(0); \
    asm volatile("s_waitcnt " VMW ::: "memory"); \
    __builtin_amdgcn_s_barrier(); \
  }

    SA(0, 0, 0); SB(0, 0, 0); SA(0, 1, 0); SB(0, 1, 0); SA(1, 0, 1); SB(1, 0, 1);
    asm volatile("s_waitcnt vmcnt(8)" ::: "memory");
    __builtin_amdgcn_s_barrier();

    const int NI = K >> 7;
    for (int j = 0; j < NI - 1; ++j) {
        const int t = 2 * j;
        PHASE(0, 0, SA(t + 1, 1, 1) SB(t + 1, 1, 1), "vmcnt(8)")
        PHASE(0, 1, SA(t + 2, 0, 0) SB(t + 2, 0, 0), "vmcnt(8)")
        PHASE(1, 0, SA(t + 2, 1, 0) SB(t + 2, 1, 0), "vmcnt(8)")
        PHASE(1, 1, SA(t + 3, 0, 1) SB(t + 3, 0, 1), "vmcnt(8)")
    }
    {
        const int t = 2 * (NI - 1);
        PHASE(0, 0, SA(t + 1, 1, 1) SB(t + 1, 1, 1), "vmcnt(8)")
        PHASE(0, 1, ((void)0),                       "vmcnt(4)")
        PHASE(1, 0, ((void)0),                       "vmcnt(0)")
        PHASE(1, 1, ((void)0),                       "vmcnt(0)")
    }
#undef PHASE
#undef SA
#undef SB
#undef REGOFF

    // ---------------- epilogue ----------------
    const long cb = QKV ? 0 : (long)z * sC;
    const int row0 = tm * 256 + wr * 128 + (l >> 4) * 4;
    const int col0 = tn * 256 + wc * 64 + rl;

    if (QKV && gsel == 2) {
        // V: write directly transposed as Vt[b][c][m]; EPI0-style NT read-back
        float b4[4];
        #pragma unroll
        for (int n = 0; n < 4; ++n) b4[n] = bias[col0 + n * 16];
        unsigned short* vout = (unsigned short*)Cout;
        const int bz = tm >> 1, mb = (tm & 1) * 256;
        #pragma unroll
        for (int hc = 0; hc < 2; ++hc) {
            if ((wc >> 1) == hc) {
                #pragma unroll
                for (int mi = 0; mi < 8; ++mi)
                    #pragma unroll
                    for (int n = 0; n < 4; ++n)
                        #pragma unroll
                        for (int r = 0; r < 4; ++r) {
                            const int lc = (wc & 1) * 64 + n * 16 + rl;
                            const int m  = wr * 128 + mi * 16 + ((l >> 4) << 2) + r;
                            lds[lc * 264 + m] = f2bf(acc[mi][n][r] + b4[n]);
                        }
            }
            __syncthreads();
            #pragma unroll
            for (int rr = 0; rr < 8; ++rr) {
                const int row = rr * 16 + (tid >> 5);
                const int ch = tid & 31;
                short8 vv = *(const short8*)&lds[row * 264 + ch * 8];
                __builtin_nontemporal_store(vv,
                    (short8*)&vout[(size_t)bz * 655360
                        + (size_t)(tn * 256 + hc * 128 + row) * 512 + mb + ch * 8]);
            }
            __syncthreads();
        }
    } else if (EPI == 0) {
        float b4[4];
        #pragma unroll
        for (int n = 0; n < 4; ++n) b4[n] = bias[col0 + n * 16];
        unsigned short* gout = (unsigned short*)Cout;
        #pragma unroll
        for (int half = 0; half < 2; ++half) {
            if (wr == half) {
                #pragma unroll
                for (int mi = 0; mi < 8; ++mi)
                    #pragma unroll
                    for (int n = 0; n < 4; ++n)
                        #pragma unroll
                        for (int r = 0; r < 4; ++r) {
                            const int lr = mi * 16 + ((l >> 4) << 2) + r;
                            const int lc = wc * 64 + n * 16 + rl;
                            lds[lr * 264 + lc] = f2bf(acc[mi][n][r] + b4[n]);
                        }
            }
            __syncthreads();
            const long rbase = (long)(tm * 256 + half * 128);
            #pragma unroll
            for (int rr = 0; rr < 8; ++rr) {
                const int row = rr * 16 + (tid >> 5);
                const int ch = tid & 31;
                short8 vv = *(const short8*)&lds[row * 264 + ch * 8];
                __builtin_nontemporal_store(vv,
                    (short8*)&gout[(rbase + row) * (size_t)ldc + tn * 256 + ch * 8]);
            }
            __syncthreads();
        }
    } else {
        #pragma unroll
        for (int mi = 0; mi < 8; ++mi) {
            #pragma unroll
            for (int n = 0; n < 4; ++n) {
                #pragma unroll
                for (int r = 0; r < 4; ++r) {
                    const int row = row0 + mi * 16 + r;
                    const int col = col0 + n * 16;
                    float v = acc[mi][n][r];
                    if (EPI == 3) v += bias[col];
                    if (EPI == 3)
                        __builtin_nontemporal_store(v, &((float*)Cout)[cb + (long)row * ldc + col]);
                    else
                        ((unsigned short*)Cout)[cb + (long)row * ldc + col] = f2bf(v);
                }
            }
        }
    }
}

// ---------------------------------------------------------------------------
// Fused scores + masked softmax: Pt[b][n][m] (verified r14, 647us).
// ---------------------------------------------------------------------------
__global__ __launch_bounds__(512, 2) void qk_softmax(
    const unsigned short* __restrict__ Q, const unsigned short* __restrict__ Km,
    unsigned short* __restrict__ Pt, const int* __restrict__ mask, float scale)
{
    __shared__ unsigned short lds[65536];

    const unsigned gx = gridDim.x;
    unsigned lin = blockIdx.x + gx * blockIdx.z;
    const unsigned nwg = gx * gridDim.z;                // 256, %8==0
    lin = (lin & 7u) * (nwg >> 3) + (lin >> 3);
    const int tm = lin % gx;
    const int z  = lin / gx;

    const unsigned short* Ab = Q  + (size_t)z * 655360 + (size_t)(tm * 128) * 1280;
    const unsigned short* Bb = Km + (size_t)z * 655360;

    const int tid = threadIdx.x, wave = tid >> 6, l = tid & 63;
    const int wr = wave >> 2, wc = wave & 3;
    const int rl = l & 15, lh = l >> 4;

    const int schunk = ((l & 3) ^ ((l >> 3) & 3)) * 8;
    const unsigned short* agS = Ab + (size_t)(wave * 16 + (l >> 2)) * 1280 + schunk;
    const unsigned short* bgS = Bb + (size_t)(wave * 16 + (l >> 2)) * 1280 + schunk;
    unsigned short* ldsA = &lds[wave * 512];
    unsigned short* ldsB = &lds[4096 + wave * 512];

    const int cl8 = ((l >> 4) ^ ((l >> 1) & 3)) * 8;
    const int aoff = (wr * 64 + rl) * 32 + cl8;
    const int boff = 4096 + (wc * 128 + rl) * 32 + cl8;

#define SLOT(s) ((s) * 20480)
#define SAQ(t, s) { GLD16(agS + (size_t)(t) * 32, ldsA + SLOT(s)); }
#define SBQ(t, s) { const unsigned short* g_ = bgS + (size_t)(t) * 32; \
    GLD16(g_,                       ldsB + SLOT(s)); \
    GLD16(g_ + (size_t)128 * 1280,  ldsB + SLOT(s) + 4096); \
    GLD16(g_ + (size_t)256 * 1280,  ldsB + SLOT(s) + 8192); \
    GLD16(g_ + (size_t)384 * 1280,  ldsB + SLOT(s) + 12288); }

    f32x4 acc[4][8] = {};

    SAQ(0, 0) SBQ(0, 0) SAQ(1, 1) SBQ(1, 1)
    asm volatile("s_waitcnt vmcnt(5)" ::: "memory");
    __builtin_amdgcn_s_barrier();

    int g0 = 0;
    for (int t = 0; t < 40; ++t) {
        const int base = g0 * 20480;
        int g2 = g0 + 2; if (g2 >= 3) g2 -= 3;
        const bool stg = (t + 2 < 40);
        short8 af[4], bfv[8];
        #pragma unroll
        for (int i = 0; i < 4; ++i) af[i] = *(const short8*)&lds[base + aoff + i * 512];
        #pragma unroll
        for (int n = 0; n < 8; ++n) bfv[n] = *(const short8*)&lds[base + boff + n * 512];
        if (stg) { SAQ(t + 2, g2) SBQ(t + 2, g2) }
        __builtin_amdgcn_s_setprio(1);
        #pragma unroll
        for (int i = 0; i < 4; ++i)
            #pragma unroll
            for (int n = 0; n < 8; ++n)
                acc[i][n] = __builtin_amdgcn_mfma_f32_16x16x32_bf16(af[i], bfv[n], acc[i][n], 0, 0, 0);
        __builtin_amdgcn_s_setprio(0);
        if (stg) { asm volatile("s_waitcnt vmcnt(5)" ::: "memory"); }
        else     { asm volatile("s_waitcnt vmcnt(0)" ::: "memory"); }
        __builtin_amdgcn_s_barrier();
        g0 = (g0 == 2) ? 0 : g0 + 1;
    }
#undef SAQ
#undef SBQ
#undef SLOT

    const int col0 = wc * 128 + rl;
    {
        const int* mb = mask + (size_t)z * 262144;
        #pragma unroll
        for (int mi = 0; mi < 4; ++mi)
            #pragma unroll
            for (int r = 0; r < 4; ++r) {
                const int m = tm * 128 + wr * 64 + mi * 16 + lh * 4 + r;
                const int* mp = mb + (size_t)m * 512 + col0;
                #pragma unroll
                for (int nj = 0; nj < 8; ++nj) {
                    float x = acc[mi][nj][r] * scale;
                    if (mp[nj * 16] == 0) x = -2.795084971874737e18f;
                    acc[mi][nj][r] = x;
                }
            }
    }
    float* red = (float*)lds;
    float rmx[4][4], rinv[4][4];
    #pragma unroll
    for (int mi = 0; mi < 4; ++mi)
        #pragma unroll
        for (int r = 0; r < 4; ++r) {
            float mx = acc[mi][0][r];
            #pragma unroll
            for (int nj = 1; nj < 8; ++nj) mx = fmaxf(mx, acc[mi][nj][r]);
            mx = fmaxf(mx, __shfl_xor(mx, 1));
            mx = fmaxf(mx, __shfl_xor(mx, 2));
            mx = fmaxf(mx, __shfl_xor(mx, 4));
            mx = fmaxf(mx, __shfl_xor(mx, 8));
            if (rl == 0) red[wc * 128 + wr * 64 + mi * 16 + lh * 4 + r] = mx;
        }
    __syncthreads();
    #pragma unroll
    for (int mi = 0; mi < 4; ++mi)
        #pragma unroll
        for (int r = 0; r < 4; ++r) {
            const int rowl = wr * 64 + mi * 16 + lh * 4 + r;
            rmx[mi][r] = fmaxf(fmaxf(red[rowl], red[128 + rowl]),
                               fmaxf(red[256 + rowl], red[384 + rowl]));
        }
    __syncthreads();
    #pragma unroll
    for (int mi = 0; mi < 4; ++mi)
        #pragma unroll
        for (int r = 0; r < 4; ++r) {
            float s = 0.f;
            #pragma unroll
            for (int nj = 0; nj < 8; ++nj) {
                float e = __expf(acc[mi][nj][r] - rmx[mi][r]);
                acc[mi][nj][r] = e; s += e;
            }
            s += __shfl_xor(s, 1); s += __shfl_xor(s, 2);
            s += __shfl_xor(s, 4); s += __shfl_xor(s, 8);
            if (rl == 0) red[wc * 128 + wr * 64 + mi * 16 + lh * 4 + r] = s;
        }
    __syncthreads();
    #pragma unroll
    for (int mi = 0; mi < 4; ++mi)
        #pragma unroll
        for (int r = 0; r < 4; ++r) {
            const int rowl = wr * 64 + mi * 16 + lh * 4 + r;
            rinv[mi][r] = 1.0f / (red[rowl] + red[128 + rowl] + red[256 + rowl] + red[384 + rowl]);
        }
    unsigned short* Pb = Pt + (size_t)z * 262144 + (size_t)tm * 128;
    #pragma unroll
    for (int nh = 0; nh < 2; ++nh) {
        __syncthreads();
        if ((wc >> 1) == nh) {
            #pragma unroll
            for (int mi = 0; mi < 4; ++mi)
                #pragma unroll
                for (int nj = 0; nj < 8; ++nj)
                    #pragma unroll
                    for (int r = 0; r < 4; ++r) {
                        const int cl = (wc & 1) * 128 + nj * 16 + rl;
                        const int rowl = wr * 64 + mi * 16 + lh * 4 + r;
                        lds[cl * 132 + rowl] = f2bf(acc[mi][nj][r] * rinv[mi][r]);
                    }
        }
        __syncthreads();
        #pragma unroll
        for (int rr = 0; rr < 8; ++rr) {
            const int nl = rr * 32 + (tid >> 4);
            const int ch = tid & 15;
            short8 vv = *(const short8*)&lds[nl * 132 + ch * 8];
            *(short8*)&Pb[(size_t)(nh * 256 + nl) * 512 + ch * 8] = vv;
        }
    }
}

// ---------------------------------------------------------------------------
// Transpose+cast the four 1280x1280 f32 weights -> Wt[j][k] bf16
// ---------------------------------------------------------------------------
__global__ void transpose_w(const float* __restrict__ Wq, const float* __restrict__ Wk,
                            const float* __restrict__ Wv, const float* __restrict__ Wr,
                            unsigned short* __restrict__ Wt)
{
    const float* W = blockIdx.z == 0 ? Wq : blockIdx.z == 1 ? Wk : blockIdx.z == 2 ? Wv : Wr;
    unsigned short* dst = Wt + (size_t)blockIdx.z * 1280 * 1280;
    __shared__ float T[64][65];
    const int j0 = blockIdx.x * 64, k0 = blockIdx.y * 64;
    const int tid = threadIdx.x;
    for (int it = 0; it < 16; ++it) {
        int idx = it * 256 + tid;
        int r = idx >> 6, c = idx & 63;
        T[r][c] = W[(size_t)(k0 + r) * 1280 + j0 + c];
    }
    __syncthreads();
    for (int it = 0; it < 16; ++it) {
        int idx = it * 256 + tid;
        int r = idx >> 6, c = idx & 63;
        dst[(size_t)(j0 + r) * 1280 + k0 + c] = f2bf(T[c][r]);
    }
}

// ---------------------------------------------------------------------------
// Cast x f32 -> bf16, vectorized
// ---------------------------------------------------------------------------
__global__ void cast_x(const float* __restrict__ x, unsigned short* __restrict__ xb, long n)
{
    long i = ((long)blockIdx.x * 256 + threadIdx.x) * 8;
    if (i + 8 > n) return;
    const float4* p = (const float4*)(x + i);
    float4 a = p[0], b = p[1];
    unsigned short o[8] = { f2bf(a.x), f2bf(a.y), f2bf(a.z), f2bf(a.w),
                            f2bf(b.x), f2bf(b.y), f2bf(b.z), f2bf(b.w) };
    *(short8*)(xb + i) = *(short8*)o;
}

// ---------------------------------------------------------------------------
extern "C" void kernel_launch(void* const* d_in, const int* in_sizes, int n_in,
                              void* d_out, int out_size, void* d_ws, size_t ws_size,
                              hipStream_t stream)
{
    const float* x   = (const float*)d_in[0];
    const int*  Mask = (const int*)d_in[1];
    const float* Wq  = (const float*)d_in[2];
    const float* bq  = (const float*)d_in[3];
    const float* Wk  = (const float*)d_in[4];
    const float* bk  = (const float*)d_in[5];
    const float* Wv  = (const float*)d_in[6];
    const float* bv  = (const float*)d_in[7];
    const float* Wr  = (const float*)d_in[8];
    const float* br  = (const float*)d_in[9];

    constexpr int N = 512, C = 1280;
    constexpr long MN = 32768;   // B*N

    char* ws = (char*)d_ws;
    unsigned short* xb = (unsigned short*)ws;                         // MN*C bf16 (later: att)
    unsigned short* Wt = (unsigned short*)(ws + 83886080);            // 4*C*C bf16
    unsigned short* Q  = (unsigned short*)(ws + 83886080 + 13107200); // MN*C
    unsigned short* Km = Q + 41943040;
    unsigned short* VtD = Km + 41943040;                              // Vt[b][c][m] (QKV g==2)
    unsigned short* Pt = VtD + 41943040;                              // B*N*N
    unsigned short* att = xb;   // alias: xb dead after QKV GEMMs

    const float scale = 0.02795084971874737f;   // 1/sqrt(1280)

    transpose_w<<<dim3(20, 20, 4), 256, 0, stream>>>(Wq, Wk, Wv, Wr, Wt);
    cast_x<<<dim3(20480), 256, 0, stream>>>(x, xb, MN * C);

    // fused QKV projections: M=32768, N=3x1280, K=1280; tn/5 selects group.
    // Group 2 (V) writes directly transposed into VtD (slot 2 = Q + 2*sC).
    gemm256<0, 1><<<dim3(15, 128, 1), 512, 0, stream>>>(xb, Wt, (void*)Q, bq, bk, bv,
        C, C, C, C, 0, 1638400L, 41943040L);

    // fused scores+softmax: Pt[b][n][m] = softmax(scale*Q.K^T, mask)
    qk_softmax<<<dim3(4, 1, 64), 512, 0, stream>>>(Q, Km, Pt, Mask, scale);

    // att[b][n][c] = sum_m Pt[b][n][m] * VtD[b][c][m]   (M=512, N=1280, K=512)
    gemm256<2, 0><<<dim3(5, 2, 64), 512, 0, stream>>>(Pt, VtD, (void*)att, nullptr, nullptr, nullptr,
        N, N, N, C, (long)N * N, (long)C * N, (long)N * C);

    // out = att @ Wr + br   (f32)
    gemm256<3, 0><<<dim3(5, 128, 1), 512, 0, stream>>>(att, Wt + 3 * 1638400, d_out, br, nullptr, nullptr,
        C, C, C, C, 0, 0, 0);
}